// Round 1
// 91.299 us; speedup vs baseline: 1.0123x; 1.0123x over previous
//
#include <hip/hip_runtime.h>

#define SCALING 0.17677669529663687f   // HD^-0.5

typedef __attribute__((ext_vector_type(8))) short bf8;      // 8 bf16
typedef __attribute__((ext_vector_type(4))) short bf4;      // 4 bf16
typedef _Float16 half8 __attribute__((ext_vector_type(8))); // 8 f16
typedef _Float16 half4 __attribute__((ext_vector_type(4))); // 4 f16
typedef __attribute__((ext_vector_type(4))) float floatx4;  // MFMA C/D

// Hardware packed f32->bf16 (RTNE) — 1 instr per 2 elems vs ~4 VALU ops/elem emulated.
__device__ __forceinline__ int cvt_pk_bf16(float a, float b) {
    int r;
    asm("v_cvt_pk_bf16_f32 %0, %1, %2" : "=v"(r) : "v"(a), "v"(b));
    return r;
}
__device__ __forceinline__ bf4 cvt4_bf(float4 x) {
    union { int i[2]; bf4 v; } u;
    u.i[0] = cvt_pk_bf16(x.x, x.y);
    u.i[1] = cvt_pk_bf16(x.z, x.w);
    return u.v;
}
__device__ __forceinline__ short f2bf_hw(float f) {
    return (short)cvt_pk_bf16(f, f);   // low 16 bits = bf16(f), RTNE
}

#define PSTR 264   // Pl row stride (shorts): 132 dwords == 4 mod 32 -> 2-way (free)
#define VSTR 72    // Vt/Ps row stride (halfs): 36 dwords == 4 mod 32 -> 2-way (free)

// ---------------------------------------------------------------------------
// Prep kernel: W (f32, 256x256) -> bf16 once into workspace.  Removes all W
// conversion + LDS staging from the fused kernel's inner loop.
// ---------------------------------------------------------------------------
__global__ void prep_w_kernel(const float* __restrict__ W, short* __restrict__ Wb) {
    int i = (blockIdx.x * 256 + threadIdx.x) * 4;   // 64 blocks x 256 thr x 4 = 65536
    float4 w = *(const float4*)(W + i);
    *(bf4*)(Wb + i) = cvt4_bf(w);
}

// ---------------------------------------------------------------------------
// Fused kernel.  Block = (n-tile of 32, batch).  512 threads, 1 block/CU.
// Phase 1 (pipelined, ONE barrier/K-step):
//   As double-buffered; A-loads issued 2 K-steps ahead; W B-fragments loaded
//   directly from global bf16 (L2-resident) 1 step ahead; hw cvt_pk converts.
// Phase 2: one head per wave (unchanged from previous version).
// ---------------------------------------------------------------------------
__global__ __launch_bounds__(512, 2) void fused_kernel(
    const float* __restrict__ q, const float* __restrict__ k,
    const float* __restrict__ v, const short* __restrict__ Wb,
    const float* __restrict__ bias, float* __restrict__ out)
{
    __shared__ short    Pl[96][PSTR];     // 50688 B  projected Q|K (bf16)
    __shared__ _Float16 Vt[256][VSTR];    // 36864 B  projected V, [d][i] (f16)
    __shared__ _Float16 Ps[8][32][VSTR];  // 36864 B  per-wave P scratch (f16)
    __shared__ short    As[2][160][40];   // 25600 B  X staging, double-buffered
                                          // total 150016 B (fits 160 KiB)

    const int tid = threadIdx.x;
    // XCD-aware swizzle: 128 n-tiles, 8 XCDs, 128%8==0 -> bijective.
    // Adjacent logical tiles (sharing 32 of 64 K/V window rows) land on the
    // same XCD's L2.
    const int bxr = blockIdx.x;
    const int bx  = (bxr & 7) * 16 + (bxr >> 3);
    const int n0  = bx * 32;
    const int b   = blockIdx.y;
    const int lane = tid & 63, wid = tid >> 6;
    const int wm = wid & 1, wn = wid >> 1;       // 2m x 4n wave grid
    const int quad = lane >> 4, l16 = lane & 15;

    // ---- Phase 1 A-staging coords ----
    // rows: r<32 -> q row n0+r; 32<=r<96 -> k row j=n0+r-64; 96<=r<160 -> v row j=n0+r-128
    int a_row[3]; int a_c4[3]; const float* a_ptr[3];
    #pragma unroll
    for (int i = 0; i < 3; i++) {
        int idx = tid + i * 512;
        if (idx < 1280) {
            int r = idx >> 3;
            a_row[i] = r;
            a_c4[i]  = (idx & 7) * 4;
            const float* p;
            if (r < 32) {
                p = q + (size_t)(b * 4096 + n0 + r) * 256;
            } else if (r < 96) {
                int j = n0 + r - 64;
                p = (j >= 0) ? (k + (size_t)(b * 4096 + j) * 256) : nullptr;
            } else {
                int j = n0 + r - 128;
                p = (j >= 0) ? (v + (size_t)(b * 4096 + j) * 256) : nullptr;
            }
            a_ptr[i] = p;
        } else { a_row[i] = -1; a_c4[i] = 0; a_ptr[i] = nullptr; }
    }

    // Per-wave W B-fragment base pointers (direct global bf16; no LDS staging)
    const short* wfp[4];
    #pragma unroll
    for (int nt = 0; nt < 4; nt++)
        wfp[nt] = Wb + (size_t)(wn * 64 + nt * 16 + l16) * 256 + quad * 8;

    floatx4 acc[5][4];
    #pragma unroll
    for (int mt = 0; mt < 5; mt++)
        #pragma unroll
        for (int nt = 0; nt < 4; nt++) acc[mt][nt] = (floatx4)0.0f;

    // ---- pipeline prologue ----
    float4 xain[3];
    #pragma unroll
    for (int i = 0; i < 3; i++) {
        xain[i] = make_float4(0.f, 0.f, 0.f, 0.f);
        if (a_ptr[i]) xain[i] = *(const float4*)(a_ptr[i] + a_c4[i]);
    }
    #pragma unroll
    for (int i = 0; i < 3; i++) {          // convert + stage tile 0 into As[0]
        bf4 t = cvt4_bf(xain[i]);
        if (a_row[i] >= 0) *(bf4*)&As[0][a_row[i]][a_c4[i]] = t;
    }
    #pragma unroll
    for (int i = 0; i < 3; i++) {          // tile 1 A-loads in flight
        float4 t = make_float4(0.f, 0.f, 0.f, 0.f);
        if (a_ptr[i]) t = *(const float4*)(a_ptr[i] + 32 + a_c4[i]);
        xain[i] = t;
    }
    bf8 wf_cur[4], wf_nxt[4];
    #pragma unroll
    for (int nt = 0; nt < 4; nt++)         // W frags for step 0 in flight
        wf_cur[nt] = *(const bf8*)(wfp[nt]);

    // ---- main K-loop: ONE barrier per step, latency hidden under MFMA ----
    for (int it = 0; it < 8; ++it) {
        const int cur = it & 1;
        __syncthreads();                   // As[cur] (tile it) visible
        bf8 af[5];
        #pragma unroll
        for (int mt = 0; mt < 5; mt++)
            af[mt] = *(const bf8*)&As[cur][wm * 80 + mt * 16 + l16][quad * 8];
        if (it < 7) {
            // convert tile it+1 (loaded last step) and stage into other buffer
            #pragma unroll
            for (int i = 0; i < 3; i++) {
                bf4 t = cvt4_bf(xain[i]);
                if (a_row[i] >= 0) *(bf4*)&As[cur ^ 1][a_row[i]][a_c4[i]] = t;
            }
            #pragma unroll
            for (int nt = 0; nt < 4; nt++)
                wf_nxt[nt] = *(const bf8*)(wfp[nt] + (it + 1) * 32);
        }
        if (it < 6) {
            // issue A-loads two steps ahead
            #pragma unroll
            for (int i = 0; i < 3; i++) {
                float4 t = make_float4(0.f, 0.f, 0.f, 0.f);
                if (a_ptr[i]) t = *(const float4*)(a_ptr[i] + (it + 2) * 32 + a_c4[i]);
                xain[i] = t;
            }
        }
        #pragma unroll
        for (int mt = 0; mt < 5; mt++)
            #pragma unroll
            for (int nt = 0; nt < 4; nt++)
                acc[mt][nt] = __builtin_amdgcn_mfma_f32_16x16x32_bf16(
                    af[mt], wf_cur[nt], acc[mt][nt], 0, 0, 0);
        #pragma unroll
        for (int nt = 0; nt < 4; nt++) wf_cur[nt] = wf_nxt[nt];
    }

    // Epilogue: +bias; Q rows pre-scaled by SCALING -> Pl; K -> Pl; V -> Vt^T
    #pragma unroll
    for (int nt = 0; nt < 4; nt++) {
        int col = wn * 64 + nt * 16 + l16;
        float bv = bias[col];
        #pragma unroll
        for (int mt = 0; mt < 5; mt++) {
            int rb = wm * 80 + mt * 16 + quad * 4;   // wave-uniform band per (wm,mt)
            if (rb < 96) {
                const bool isQ = (rb < 32);
                #pragma unroll
                for (int r = 0; r < 4; r++) {
                    float val = acc[mt][nt][r] + bv;
                    Pl[rb + r][col] = f2bf_hw(isQ ? val * SCALING : val);
                }
            } else {
                half4 hv;
                #pragma unroll
                for (int r = 0; r < 4; r++) hv[r] = (_Float16)(acc[mt][nt][r] + bv);
                *(half4*)&Vt[col][rb - 96] = hv;
            }
        }
    }
    __syncthreads();

    // ---- Phase 2: one head per wave ----
    const int h  = wid;
    const int cb = h * 32;

    // S = Q.K^T : A-frags from Q rows, B-frags from K rows (both contiguous-d)
    bf8 qf[2], kf[4];
    #pragma unroll
    for (int mt = 0; mt < 2; mt++)
        qf[mt] = *(const bf8*)&Pl[mt * 16 + l16][cb + quad * 8];
    #pragma unroll
    for (int jt = 0; jt < 4; jt++)
        kf[jt] = *(const bf8*)&Pl[32 + jt * 16 + l16][cb + quad * 8];

    floatx4 S[2][4];
    S[0][0] = __builtin_amdgcn_mfma_f32_16x16x32_bf16(qf[0], kf[0], (floatx4)0.f, 0, 0, 0);
    S[0][1] = __builtin_amdgcn_mfma_f32_16x16x32_bf16(qf[0], kf[1], (floatx4)0.f, 0, 0, 0);
    S[0][2] = __builtin_amdgcn_mfma_f32_16x16x32_bf16(qf[0], kf[2], (floatx4)0.f, 0, 0, 0);
    S[1][1] = __builtin_amdgcn_mfma_f32_16x16x32_bf16(qf[1], kf[1], (floatx4)0.f, 0, 0, 0);
    S[1][2] = __builtin_amdgcn_mfma_f32_16x16x32_bf16(qf[1], kf[2], (floatx4)0.f, 0, 0, 0);
    S[1][3] = __builtin_amdgcn_mfma_f32_16x16x32_bf16(qf[1], kf[3], (floatx4)0.f, 0, 0, 0);

    // Band mask + softmax.  Row n = mt*16+quad*4+r; col i = jt*16+l16;
    // valid iff n+1 <= i <= n+32.  Row stats via shfl_xor over l16 group.
    float p[2][3][4], inv[2][4];
    #pragma unroll
    for (int mt = 0; mt < 2; mt++) {
        #pragma unroll
        for (int r = 0; r < 4; r++) {
            int n = mt * 16 + quad * 4 + r;
            float sv[3], mx = -3.0e38f;
            #pragma unroll
            for (int u = 0; u < 3; u++) {
                int i = (u + mt) * 16 + l16;
                bool valid = (i > n) && (i <= n + 32);
                sv[u] = valid ? S[mt][u + mt][r] : -3.0e38f;
                mx = fmaxf(mx, sv[u]);
            }
            #pragma unroll
            for (int off = 1; off < 16; off <<= 1)
                mx = fmaxf(mx, __shfl_xor(mx, off, 64));
            float lsum = 0.f;
            #pragma unroll
            for (int u = 0; u < 3; u++) {
                float pv = (sv[u] > -1.0e38f) ? __expf(sv[u] - mx) : 0.f;
                p[mt][u][r] = pv;
                lsum += pv;
            }
            #pragma unroll
            for (int off = 1; off < 16; off <<= 1)
                lsum += __shfl_xor(lsum, off, 64);
            inv[mt][r] = 1.0f / lsum;
        }
    }

    // P -> per-wave scratch (f16), C-layout writes; zero out-of-band tiles
    _Float16 (*myPs)[VSTR] = Ps[h];
    #pragma unroll
    for (int mt = 0; mt < 2; mt++) {
        int zjt = (mt == 0) ? 3 : 0;
        #pragma unroll
        for (int r = 0; r < 4; r++) {
            int row = mt * 16 + quad * 4 + r;
            #pragma unroll
            for (int u = 0; u < 3; u++)
                myPs[row][(u + mt) * 16 + l16] = (_Float16)p[mt][u][r];
            myPs[row][zjt * 16 + l16] = (_Float16)0.f;
        }
    }
    // same-wave producer/consumer: compiler inserts lgkmcnt wait

    half8 pf[2][2], vf[2][2];
    #pragma unroll
    for (int mt = 0; mt < 2; mt++)
        #pragma unroll
        for (int ks = 0; ks < 2; ks++)
            pf[mt][ks] = *(const half8*)&myPs[mt * 16 + l16][ks * 32 + quad * 8];
    #pragma unroll
    for (int dt = 0; dt < 2; dt++)
        #pragma unroll
        for (int ks = 0; ks < 2; ks++)
            vf[dt][ks] = *(const half8*)&Vt[cb + dt * 16 + l16][ks * 32 + quad * 8];

    floatx4 O[2][2];
    #pragma unroll
    for (int mt = 0; mt < 2; mt++)
        #pragma unroll
        for (int dt = 0; dt < 2; dt++) {
            O[mt][dt] = (floatx4)0.f;
            #pragma unroll
            for (int ks = 0; ks < 2; ks++)
                O[mt][dt] = __builtin_amdgcn_mfma_f32_16x16x32_f16(
                    pf[mt][ks], vf[dt][ks], O[mt][dt], 0, 0, 0);
        }

    // Store: O row n = mt*16+quad*4+r, col e = cb+dt*16+l16; scale by 1/l
    const size_t obase = ((size_t)b * 4096 + n0) * 256;
    #pragma unroll
    for (int mt = 0; mt < 2; mt++)
        #pragma unroll
        for (int dt = 0; dt < 2; dt++)
            #pragma unroll
            for (int r = 0; r < 4; r++) {
                int n = mt * 16 + quad * 4 + r;
                out[obase + (size_t)n * 256 + cb + dt * 16 + l16] =
                    O[mt][dt][r] * inv[mt][r];
            }
}

extern "C" void kernel_launch(void* const* d_in, const int* in_sizes, int n_in,
                              void* d_out, int out_size, void* d_ws, size_t ws_size,
                              hipStream_t stream) {
    (void)in_sizes; (void)n_in; (void)out_size; (void)ws_size;
    const float* q    = (const float*)d_in[0];
    const float* k    = (const float*)d_in[1];
    const float* v    = (const float*)d_in[2];
    const float* W    = (const float*)d_in[3];
    const float* bias = (const float*)d_in[4];
    float* outp = (float*)d_out;
    short* Wb   = (short*)d_ws;   // 256*256*2 = 128 KiB of workspace

    hipLaunchKernelGGL(prep_w_kernel, dim3(64), dim3(256), 0, stream, W, Wb);
    hipLaunchKernelGGL(fused_kernel, dim3(128, 2), dim3(512), 0, stream,
                       q, k, v, Wb, bias, outp);
}